// Round 1
// baseline (251.283 us; speedup 1.0000x reference)
//
#include <hip/hip_runtime.h>
#include <math.h>

#define NH      6
#define T_IN    2000
#define T_AUD   960000
#define CHUNK   256
#define NCHUNK  3750   // T_AUD / CHUNK
#define NB      4
#define C_IN    129
#define C_MID   32

// linear-interp f0 upsample at audio sample t (double precision)
__device__ __forceinline__ double f0up_at(const float* __restrict__ f0b, int t) {
    double pos = ((double)t + 0.5) * (1.0 / 480.0) - 0.5;
    pos = pos < 0.0 ? 0.0 : (pos > 1999.0 ? 1999.0 : pos);
    int i0 = (int)pos;
    int i1 = i0 + 1; if (i1 > 1999) i1 = 1999;
    double w = pos - (double)i0;
    return (double)f0b[i0] * (1.0 - w) + (double)f0b[i1] * w;
}

// ---------------- conv1 (129ch -> 32ch, k=5, pad=2) + SiLU ----------------
// grid: (8 t-tiles, 32 o, 4 b), block 256
__global__ void k_conv1(const float* __restrict__ f0, const float* __restrict__ mel,
                        const float* __restrict__ w1, const float* __restrict__ b1,
                        float* __restrict__ sil) {
    const int o  = blockIdx.y;
    const int b  = blockIdx.z;
    const int t0 = blockIdx.x * 256;
    const int tid = threadIdx.x;

    __shared__ float wl[C_IN * 5];
    __shared__ float xl[16][260];

    for (int idx = tid; idx < C_IN * 5; idx += 256) wl[idx] = w1[o * C_IN * 5 + idx];
    float acc = b1[o];

    for (int cg = 0; cg < C_IN; cg += 16) {
        const int ng = (C_IN - cg) < 16 ? (C_IN - cg) : 16;
        __syncthreads();
        for (int idx = tid; idx < ng * 260; idx += 256) {
            const int ci  = idx / 260;
            const int col = idx - ci * 260;
            const int c   = cg + ci;
            const int tt  = t0 + col - 2;
            const float* row = (c == 0) ? (f0 + b * T_IN)
                                        : (mel + ((size_t)(b * 128 + (c - 1))) * T_IN);
            xl[ci][col] = (tt >= 0 && tt < T_IN) ? row[tt] : 0.0f;
        }
        __syncthreads();
        for (int ci = 0; ci < ng; ++ci) {
            const int c = cg + ci;
            const float* wc = &wl[c * 5];
            const float x0 = xl[ci][tid + 0];
            const float x1 = xl[ci][tid + 1];
            const float x2 = xl[ci][tid + 2];
            const float x3 = xl[ci][tid + 3];
            const float x4 = xl[ci][tid + 4];
            acc = fmaf(wc[0], x0, acc);
            acc = fmaf(wc[1], x1, acc);
            acc = fmaf(wc[2], x2, acc);
            acc = fmaf(wc[3], x3, acc);
            acc = fmaf(wc[4], x4, acc);
        }
    }
    const int t = t0 + tid;
    if (t < T_IN) {
        const float sg = __builtin_amdgcn_rcpf(1.0f + __expf(-acc));
        sil[((size_t)(b * C_MID + o)) * T_IN + t] = acc * sg;
    }
}

// ---------------- conv2 (1x1, 32 -> 6) ----------------
__global__ void k_conv2(const float* __restrict__ sil, const float* __restrict__ w2,
                        const float* __restrict__ b2, float* __restrict__ amp) {
    const int g = blockIdx.x * 256 + threadIdx.x;
    if (g >= NB * NH * T_IN) return;
    const int b = g / (NH * T_IN);
    const int r = g - b * (NH * T_IN);
    const int h = r / T_IN;
    const int t = r - h * T_IN;
    float acc = b2[h];
    #pragma unroll
    for (int o = 0; o < C_MID; ++o)
        acc = fmaf(w2[h * C_MID + o], sil[((size_t)(b * C_MID + o)) * T_IN + t], acc);
    amp[g] = acc;
}

// ---------------- per-chunk phase totals (double) ----------------
// grid: (ceil(3750/4), 4), block 256 (4 waves = 4 chunks)
__global__ void k_totals(const float* __restrict__ f0, double* __restrict__ totals) {
    const int b    = blockIdx.y;
    const int lane = threadIdx.x & 63;
    const int wid  = threadIdx.x >> 6;
    const int chunk = blockIdx.x * 4 + wid;
    if (chunk >= NCHUNK) return;
    const float* f0b = f0 + b * T_IN;
    const int t0 = chunk * CHUNK + lane * 4;
    double s = 0.0;
    #pragma unroll
    for (int j = 0; j < 4; ++j) s += f0up_at(f0b, t0 + j);
    s *= (1.0 / 48000.0);
    #pragma unroll
    for (int d = 32; d >= 1; d >>= 1) s += __shfl_down(s, d, 64);
    if (lane == 0) totals[b * NCHUNK + chunk] = s;
}

// ---------------- carries: frac of exclusive prefix of totals ----------------
// grid: 4 blocks (one per b), block 256; each thread covers 15 chunks
__global__ void k_carries(const double* __restrict__ totals, double* __restrict__ carries) {
    const int b   = blockIdx.x;
    const int tid = threadIdx.x;
    const double* tb = totals + b * NCHUNK;
    double* cb = carries + b * NCHUNK;
    const int base = tid * 15;
    double psum = 0.0;
    for (int j = 0; j < 15; ++j) {
        const int n = base + j;
        if (n < NCHUNK) psum += tb[n];
    }
    __shared__ double part[256];
    part[tid] = psum;
    __syncthreads();
    double run = psum;
    for (int d = 1; d < 256; d <<= 1) {
        const double tadd = (tid >= d) ? part[tid - d] : 0.0;
        __syncthreads();
        run += tadd;
        part[tid] = run;
        __syncthreads();
    }
    double S = run - psum;  // exclusive prefix for this thread's first chunk
    for (int j = 0; j < 15; ++j) {
        const int n = base + j;
        if (n < NCHUNK) {
            cb[n] = S - floor(S);
            S += tb[n];
        }
    }
}

// ---------------- main: phase scan + harmonics + noise ----------------
// grid: (3750, 4), block 256 (one chunk per block)
__global__ void k_main(const float* __restrict__ f0, const float* __restrict__ noise,
                       const float* __restrict__ amp, const double* __restrict__ carries,
                       const float* __restrict__ amp_logscale, const float* __restrict__ phase_offset,
                       const float* __restrict__ lnv, const float* __restrict__ lnu,
                       float* __restrict__ out) {
    const int b     = blockIdx.y;
    const int chunk = blockIdx.x;
    const int tid   = threadIdx.x;
    const int lane  = tid & 63;
    const int wid   = tid >> 6;

    __shared__ double s_wsum[4];
    __shared__ float s_amp[NH], s_off[NH];
    __shared__ float s_nv, s_nu;
    if (tid < NH) {
        s_amp[tid] = __expf(amp_logscale[tid]);
        s_off[tid] = phase_offset[tid];
    } else if (tid == 8) {
        s_nv = __expf(lnv[0]);
    } else if (tid == 9) {
        s_nu = __expf(lnu[0]);
    }

    const float* f0b = f0 + b * T_IN;
    const int t = chunk * CHUNK + tid;

    const double f0u = f0up_at(f0b, t);
    double v = f0u * (1.0 / 48000.0);

    // intra-wave inclusive scan
    #pragma unroll
    for (int d = 1; d < 64; d <<= 1) {
        const double n = __shfl_up(v, d, 64);
        if (lane >= d) v += n;
    }
    if (lane == 63) s_wsum[wid] = v;
    __syncthreads();
    double cum = v;
    for (int wq = 0; wq < wid; ++wq) cum += s_wsum[wq];

    const double S = cum + carries[b * NCHUNK + chunk];
    const float ph = (float)(S - floor(S));       // base phase in revolutions, [0,1)
    const float f0uf = (float)f0u;
    const float voiced = (f0uf > 1.0f) ? 1.0f : 0.0f;

    // interp weights for amp_mod (same positions as f0 upsample)
    double posd = ((double)t + 0.5) * (1.0 / 480.0) - 0.5;
    posd = posd < 0.0 ? 0.0 : (posd > 1999.0 ? 1999.0 : posd);
    const int i0 = (int)posd;
    const int i1 = (i0 + 1 > 1999) ? 1999 : i0 + 1;
    const float w = (float)(posd - (double)i0);

    const size_t outb = (size_t)b * 7 * T_AUD;
    #pragma unroll
    for (int h = 0; h < NH; ++h) {
        const float kf = (float)(h + 1);
        const float* ab = amp + ((size_t)(b * NH + h)) * T_IN;
        const float am  = ab[i0] * (1.0f - w) + ab[i1] * w;
        const float sig = __builtin_amdgcn_rcpf(1.0f + __expf(-am));
        const float arg = kf * ph + s_off[h];          // revolutions
        const float fr  = arg - floorf(arg);
        const float sn  = __builtin_amdgcn_sinf(fr);   // sin(2*pi*fr)
        const float aaarg = (24000.0f - kf * f0uf) * (1.0f / 1200.0f);
        const float aa  = __builtin_amdgcn_rcpf(1.0f + __expf(-aaarg));
        out[outb + (size_t)h * T_AUD + t] = sn * s_amp[h] * (2.0f * sig) * (aa * voiced);
    }
    const float namp = (voiced > 0.0f) ? s_nv : s_nu;
    out[outb + (size_t)6 * T_AUD + t] = noise[(size_t)b * T_AUD + t] * namp;
}

extern "C" void kernel_launch(void* const* d_in, const int* in_sizes, int n_in,
                              void* d_out, int out_size, void* d_ws, size_t ws_size,
                              hipStream_t stream) {
    const float* f0   = (const float*)d_in[0];
    const float* mel  = (const float*)d_in[1];
    const float* nois = (const float*)d_in[2];
    const float* w1   = (const float*)d_in[3];
    const float* b1   = (const float*)d_in[4];
    const float* w2   = (const float*)d_in[5];
    const float* b2   = (const float*)d_in[6];
    const float* alog = (const float*)d_in[7];
    const float* poff = (const float*)d_in[8];
    const float* lnv  = (const float*)d_in[9];
    const float* lnu  = (const float*)d_in[10];
    float* out = (float*)d_out;

    // workspace layout (bytes):
    //   [0, 1024000)        sil      : 4*32*2000 f32
    //   [1024000, 1216000)  amp_mod  : 4*6*2000 f32
    //   [1216000, 1336000)  totals   : 4*3750 f64
    //   [1336000, 1456000)  carries  : 4*3750 f64
    float*  sil     = (float*)d_ws;
    float*  amp     = (float*)((char*)d_ws + 1024000);
    double* totals  = (double*)((char*)d_ws + 1216000);
    double* carries = (double*)((char*)d_ws + 1336000);

    k_conv1<<<dim3(8, C_MID, NB), 256, 0, stream>>>(f0, mel, w1, b1, sil);
    k_conv2<<<dim3((NB * NH * T_IN + 255) / 256), 256, 0, stream>>>(sil, w2, b2, amp);
    k_totals<<<dim3((NCHUNK + 3) / 4, NB), 256, 0, stream>>>(f0, totals);
    k_carries<<<dim3(NB), 256, 0, stream>>>(totals, carries);
    k_main<<<dim3(NCHUNK, NB), 256, 0, stream>>>(f0, nois, amp, carries,
                                                 alog, poff, lnv, lnu, out);
}

// Round 2
// 201.007 us; speedup vs baseline: 1.2501x; 1.2501x over previous
//
#include <hip/hip_runtime.h>
#include <math.h>

#define NH      6
#define T_IN    2000
#define T_AUD   960000
#define CHUNK   256
#define NCHUNK  3750   // T_AUD / CHUNK
#define NB      4
#define C_IN    129
#define C_MID   32
#define CSPLIT  3
#define NC_PER  43          // channels per c-split (43*3 = 129)
#define SPLIT_STRIDE (NB * C_MID * T_IN)   // 256000 floats

// linear-interp f0 upsample at audio sample t (double precision)
__device__ __forceinline__ double f0up_at(const float* __restrict__ f0b, int t) {
    double pos = ((double)t + 0.5) * (1.0 / 480.0) - 0.5;
    pos = pos < 0.0 ? 0.0 : (pos > 1999.0 ? 1999.0 : pos);
    int i0 = (int)pos;
    int i1 = i0 + 1; if (i1 > 1999) i1 = 1999;
    double w = pos - (double)i0;
    return (double)f0b[i0] * (1.0 - w) + (double)f0b[i1] * w;
}

// ---------------- conv1 partials (no bias), split over channels ----------------
// grid: x = 8 t-tiles, y = b*4 + og (16), z = csplit (3). block 256.
// Each thread: one t, 8 output channels, 43 input channels.
__global__ void k_conv1(const float* __restrict__ f0, const float* __restrict__ mel,
                        const float* __restrict__ w1, float* __restrict__ hpart) {
    const int t0  = blockIdx.x * 256;
    const int b   = blockIdx.y >> 2;
    const int o0  = (blockIdx.y & 3) * 8;
    const int z   = blockIdx.z;
    const int cbase = z * NC_PER;
    const int tid = threadIdx.x;

    // staged cols [t0-4, t0+260) = 264 cols = 66 float4 per row
    __shared__ float xl[NC_PER][264];

    // ---- stage input tile (float4, coalesced) ----
    for (int idx = tid; idx < NC_PER * 66; idx += 256) {
        const int r = idx / 66;
        const int j = idx - r * 66;
        const int c = cbase + r;              // global input channel
        const float* row = (c == 0) ? (f0 + b * T_IN)
                                    : (mel + ((size_t)(b * 128 + (c - 1))) * T_IN);
        const int gt = t0 - 4 + j * 4;
        float4 v;
        if (gt >= 0 && gt + 3 < T_IN) {
            v = *(const float4*)(row + gt);
        } else {
            v.x = (gt + 0 >= 0 && gt + 0 < T_IN) ? row[gt + 0] : 0.0f;
            v.y = (gt + 1 >= 0 && gt + 1 < T_IN) ? row[gt + 1] : 0.0f;
            v.z = (gt + 2 >= 0 && gt + 2 < T_IN) ? row[gt + 2] : 0.0f;
            v.w = (gt + 3 >= 0 && gt + 3 < T_IN) ? row[gt + 3] : 0.0f;
        }
        *(float4*)(&xl[r][j * 4]) = v;
    }
    __syncthreads();

    float acc[8];
    #pragma unroll
    for (int oo = 0; oo < 8; ++oo) acc[oo] = 0.0f;

    for (int c = 0; c < NC_PER; ++c) {
        const float x0 = xl[c][tid + 2];
        const float x1 = xl[c][tid + 3];
        const float x2 = xl[c][tid + 4];
        const float x3 = xl[c][tid + 5];
        const float x4 = xl[c][tid + 6];
        const int cg = cbase + c;
        #pragma unroll
        for (int oo = 0; oo < 8; ++oo) {
            // wave-uniform index -> scalar loads (SGPR operands for the FMAs)
            const float* wp = w1 + (size_t)(o0 + oo) * (C_IN * 5) + cg * 5;
            acc[oo] = fmaf(wp[0], x0, acc[oo]);
            acc[oo] = fmaf(wp[1], x1, acc[oo]);
            acc[oo] = fmaf(wp[2], x2, acc[oo]);
            acc[oo] = fmaf(wp[3], x3, acc[oo]);
            acc[oo] = fmaf(wp[4], x4, acc[oo]);
        }
    }

    const int t = t0 + tid;
    if (t < T_IN) {
        #pragma unroll
        for (int oo = 0; oo < 8; ++oo)
            hpart[(size_t)z * SPLIT_STRIDE + ((size_t)(b * C_MID + o0 + oo)) * T_IN + t] = acc[oo];
    }
}

// ---------------- conv2: sum partials + bias, silu, 1x1 conv ----------------
__global__ void k_conv2(const float* __restrict__ hpart, const float* __restrict__ b1,
                        const float* __restrict__ w2, const float* __restrict__ b2,
                        float* __restrict__ amp) {
    const int g = blockIdx.x * 256 + threadIdx.x;
    if (g >= NB * NH * T_IN) return;
    const int b = g / (NH * T_IN);
    const int r = g - b * (NH * T_IN);
    const int h = r / T_IN;
    const int t = r - h * T_IN;
    float acc = b2[h];
    #pragma unroll
    for (int o = 0; o < C_MID; ++o) {
        const size_t base = ((size_t)(b * C_MID + o)) * T_IN + t;
        float v = hpart[base] + hpart[SPLIT_STRIDE + base] + hpart[2 * SPLIT_STRIDE + base] + b1[o];
        const float sg = __builtin_amdgcn_rcpf(1.0f + __expf(-v));
        acc = fmaf(w2[h * C_MID + o], v * sg, acc);
    }
    amp[g] = acc;
}

// ---------------- per-chunk phase totals (double) ----------------
__global__ void k_totals(const float* __restrict__ f0, double* __restrict__ totals) {
    const int b    = blockIdx.y;
    const int lane = threadIdx.x & 63;
    const int wid  = threadIdx.x >> 6;
    const int chunk = blockIdx.x * 4 + wid;
    if (chunk >= NCHUNK) return;
    const float* f0b = f0 + b * T_IN;
    const int t0 = chunk * CHUNK + lane * 4;
    double s = 0.0;
    #pragma unroll
    for (int j = 0; j < 4; ++j) s += f0up_at(f0b, t0 + j);
    s *= (1.0 / 48000.0);
    #pragma unroll
    for (int d = 32; d >= 1; d >>= 1) s += __shfl_down(s, d, 64);
    if (lane == 0) totals[b * NCHUNK + chunk] = s;
}

// ---------------- carries: frac of exclusive prefix of totals ----------------
__global__ void k_carries(const double* __restrict__ totals, double* __restrict__ carries) {
    const int b   = blockIdx.x;
    const int tid = threadIdx.x;
    const double* tb = totals + b * NCHUNK;
    double* cb = carries + b * NCHUNK;
    const int base = tid * 15;
    double psum = 0.0;
    for (int j = 0; j < 15; ++j) {
        const int n = base + j;
        if (n < NCHUNK) psum += tb[n];
    }
    __shared__ double part[256];
    part[tid] = psum;
    __syncthreads();
    double run = psum;
    for (int d = 1; d < 256; d <<= 1) {
        const double tadd = (tid >= d) ? part[tid - d] : 0.0;
        __syncthreads();
        run += tadd;
        part[tid] = run;
        __syncthreads();
    }
    double S = run - psum;
    for (int j = 0; j < 15; ++j) {
        const int n = base + j;
        if (n < NCHUNK) {
            cb[n] = S - floor(S);
            S += tb[n];
        }
    }
}

// ---------------- main: one wave per 256-chunk, 4 samples/thread ----------------
// grid: (ceil(3750/4)=938, 4). block 256 = 4 independent waves. No barriers.
__global__ void k_main(const float* __restrict__ f0, const float* __restrict__ noise,
                       const float* __restrict__ amp, const double* __restrict__ carries,
                       const float* __restrict__ amp_logscale, const float* __restrict__ phase_offset,
                       const float* __restrict__ lnv, const float* __restrict__ lnu,
                       float* __restrict__ out) {
    const int b    = blockIdx.y;
    const int tid  = threadIdx.x;
    const int lane = tid & 63;
    const int wid  = tid >> 6;
    const int chunk = blockIdx.x * 4 + wid;
    if (chunk >= NCHUNK) return;

    const float* f0b = f0 + b * T_IN;
    const int t0 = chunk * CHUNK + lane * 4;

    double f0u[4], inc[4];
    #pragma unroll
    for (int j = 0; j < 4; ++j) {
        f0u[j] = f0up_at(f0b, t0 + j);
        inc[j] = f0u[j] * (1.0 / 48000.0);
    }
    const double loc = inc[0] + inc[1] + inc[2] + inc[3];

    // intra-wave inclusive scan of per-thread sums
    double v = loc;
    #pragma unroll
    for (int d = 1; d < 64; d <<= 1) {
        const double n = __shfl_up(v, d, 64);
        if (lane >= d) v += n;
    }
    double run = v - loc + carries[b * NCHUNK + chunk];  // exclusive + carry

    float ph[4], f0f[4], voiced[4], wgt[4];
    int i0[4], i1[4];
    #pragma unroll
    for (int j = 0; j < 4; ++j) {
        run += inc[j];                       // inclusive cumsum at this sample
        ph[j]  = (float)(run - floor(run));  // base phase, revolutions, [0,1)
        f0f[j] = (float)f0u[j];
        voiced[j] = (f0f[j] > 1.0f) ? 1.0f : 0.0f;
        double posd = ((double)(t0 + j) + 0.5) * (1.0 / 480.0) - 0.5;
        posd = posd < 0.0 ? 0.0 : (posd > 1999.0 ? 1999.0 : posd);
        i0[j] = (int)posd;
        i1[j] = (i0[j] + 1 > 1999) ? 1999 : i0[j] + 1;
        wgt[j] = (float)(posd - (double)i0[j]);
    }

    const size_t outb = (size_t)b * 7 * T_AUD;
    #pragma unroll
    for (int h = 0; h < NH; ++h) {
        const float kf = (float)(h + 1);
        const float ascale = __expf(amp_logscale[h]);
        const float off = phase_offset[h];
        const float* ab = amp + ((size_t)(b * NH + h)) * T_IN;
        float4 res;
        float r[4];
        #pragma unroll
        for (int j = 0; j < 4; ++j) {
            const float am  = ab[i0[j]] * (1.0f - wgt[j]) + ab[i1[j]] * wgt[j];
            const float sig = __builtin_amdgcn_rcpf(1.0f + __expf(-am));
            const float arg = kf * ph[j] + off;
            const float fr  = arg - floorf(arg);
            const float sn  = __builtin_amdgcn_sinf(fr);   // sin(2*pi*fr)
            const float aa  = __builtin_amdgcn_rcpf(1.0f + __expf(-(24000.0f - kf * f0f[j]) * (1.0f / 1200.0f)));
            r[j] = sn * ascale * (2.0f * sig) * (aa * voiced[j]);
        }
        res.x = r[0]; res.y = r[1]; res.z = r[2]; res.w = r[3];
        *(float4*)(out + outb + (size_t)h * T_AUD + t0) = res;
    }

    const float nv = __expf(lnv[0]);
    const float nu = __expf(lnu[0]);
    const float4 nz = *(const float4*)(noise + (size_t)b * T_AUD + t0);
    float4 no;
    no.x = nz.x * (voiced[0] > 0.0f ? nv : nu);
    no.y = nz.y * (voiced[1] > 0.0f ? nv : nu);
    no.z = nz.z * (voiced[2] > 0.0f ? nv : nu);
    no.w = nz.w * (voiced[3] > 0.0f ? nv : nu);
    *(float4*)(out + outb + (size_t)6 * T_AUD + t0) = no;
}

extern "C" void kernel_launch(void* const* d_in, const int* in_sizes, int n_in,
                              void* d_out, int out_size, void* d_ws, size_t ws_size,
                              hipStream_t stream) {
    const float* f0   = (const float*)d_in[0];
    const float* mel  = (const float*)d_in[1];
    const float* nois = (const float*)d_in[2];
    const float* w1   = (const float*)d_in[3];
    const float* b1   = (const float*)d_in[4];
    const float* w2   = (const float*)d_in[5];
    const float* b2   = (const float*)d_in[6];
    const float* alog = (const float*)d_in[7];
    const float* poff = (const float*)d_in[8];
    const float* lnv  = (const float*)d_in[9];
    const float* lnu  = (const float*)d_in[10];
    float* out = (float*)d_out;

    // workspace layout (bytes):
    //   [0, 3072000)             hpart   : 3 * 4*32*2000 f32
    //   [3072000, 3264000)       amp_mod : 4*6*2000 f32
    //   [3264000, 3384000)       totals  : 4*3750 f64
    //   [3384000, 3504000)       carries : 4*3750 f64
    float*  hpart   = (float*)d_ws;
    float*  amp     = (float*)((char*)d_ws + 3072000);
    double* totals  = (double*)((char*)d_ws + 3264000);
    double* carries = (double*)((char*)d_ws + 3384000);

    k_conv1<<<dim3(8, 16, CSPLIT), 256, 0, stream>>>(f0, mel, w1, hpart);
    k_conv2<<<dim3((NB * NH * T_IN + 255) / 256), 256, 0, stream>>>(hpart, b1, w2, b2, amp);
    k_totals<<<dim3((NCHUNK + 3) / 4, NB), 256, 0, stream>>>(f0, totals);
    k_carries<<<dim3(NB), 256, 0, stream>>>(totals, carries);
    k_main<<<dim3((NCHUNK + 3) / 4, NB), 256, 0, stream>>>(f0, nois, amp, carries,
                                                           alog, poff, lnv, lnu, out);
}